// Round 8
// baseline (525.126 us; speedup 1.0000x reference)
//
#include <hip/hip_runtime.h>

// Problem constants
#define NBATCH 8
#define CIN    64
#define HIN    256
#define WIN    256
#define COUT   128
#define HOUT   254
#define WOUT   254

// Persistent-kernel geometry: 256 blocks (1/CU) x 512 threads.
// Block owns (wt 0..7, ht 0..15, co-half 0..1); loops n=0..7.
// Tile = 512 px (16 rows x 32 cols) x 64 co; 8 waves, each 64px x 64co.
#define PROWS  16
#define PCOLS  32
#define XR     (PROWS + 2)   // 18 input rows
#define XC     (PCOLS + 2)   // 34 input cols
#define CIP    72            // sx ci stride (144B rows -> conflict-free av reads)

typedef __attribute__((ext_vector_type(8))) short bf16x8;  // MFMA A/B frag
typedef __attribute__((ext_vector_type(4))) float f32x4;   // MFMA C/D frag

__device__ __forceinline__ unsigned short f2bf(float f) {
    union { float f; unsigned u; } v; v.f = f;
    unsigned r = v.u + 0x7FFF + ((v.u >> 16) & 1);   // round-to-nearest-even
    return (unsigned short)(r >> 16);
}

// mish(v) = v*(1 - 2/((t+1)^2+1)), t=e^min(v,44). 8 insts, select-free.
__device__ __forceinline__ float mish1(float v) {
    float t = __expf(fminf(v, 44.0f));
    float s = t + 1.0f;
    float d = __builtin_fmaf(s, s, 1.0f);
    float r = __builtin_amdgcn_rcpf(d);
    return v * __builtin_fmaf(-2.0f, r, 1.0f);
}
__device__ __forceinline__ float mish2(float v) { return mish1(mish1(v)); }

// ---------------------------------------------------------------------------
// Weight pre-transform: wgt[co][ci][3][3] fp32 -> wT bf16 laid out as the
// EXACT LDS image per co-half: [half][tap][co_l 64][slot' 8][j 8], where
// slot' = (g + 4*ck) ^ (co_l & 7)  (XOR swizzle -> conflict-free bv reads),
// logical ci = ck*32 + g*8 + j. The kernel fills LDS with a linear copy.
// ---------------------------------------------------------------------------
__global__ __launch_bounds__(256) void wtrans_kernel(
    const float* __restrict__ wgt, unsigned short* __restrict__ wT)
{
    int i = blockIdx.x * 256 + threadIdx.x;       // 0 .. 73727
    if (i >= 2 * 9 * 64 * 64) return;
    int half = i / 36864;
    int r    = i - half * 36864;
    int tap  = r >> 12;                           // /4096
    int r2   = r & 4095;
    int co_l = r2 >> 6;
    int q    = r2 & 63;                           // element within 64-el row
    int s    = (q >> 3) ^ (co_l & 7);             // logical slot
    int j    = q & 7;
    int ci   = ((s >> 2) << 5) + ((s & 3) << 3) + j;   // ck*32 + g*8 + j
    int co   = half * 64 + co_l;
    wT[i] = f2bf(wgt[(co * CIN + ci) * 9 + tap]);
}

// ---------------------------------------------------------------------------
// Persistent conv kernel.
// ---------------------------------------------------------------------------
__global__ __launch_bounds__(512, 2) void conv_persist(
    const float* __restrict__ x,                  // [NB][CIN][HIN][WIN]
    const float* __restrict__ bias,               // [COUT]
    const unsigned short* __restrict__ wT,        // pre-swizzled (see wtrans)
    float* __restrict__ out)                      // [NB][COUT][HOUT][WOUT]
{
    __shared__ unsigned short sx[XR * XC * CIP];  // 88128 B
    __shared__ unsigned short wl[9 * 64 * 64];    // 73728 B  (total 161856)

    const int tid = threadIdx.x;
    const int b   = blockIdx.x;                   // 0..255
    const int half = b >> 7;                      // co half
    const int tg   = b & 127;
    const int wt   = tg & 7;
    const int ht   = tg >> 3;                     // 0..15
    const int oh0 = ht * PROWS, ow0 = wt * PCOLS;

    // ---- fill w_lds once: linear 73728-B copy (pre-swizzled by wtrans)
    {
        const bf16x8* src = (const bf16x8*)(wT + half * 36864);
        #pragma unroll
        for (int k = 0; k < 9; ++k) {
            bf16x8 v = src[k * 512 + tid];
            *(bf16x8*)&wl[(k * 512 + tid) * 8] = v;
        }
    }

    // wave/lane decomposition: 8 waves, each 64 px x 64 co
    const int w    = tid >> 6;
    const int lane = tid & 63;
    const int m    = lane & 15;                   // A: px / B,C: co
    const int g    = lane >> 4;                   // k-group (8 ci)
    const int g8   = g * 8;

    int slot0[4];                                 // sx row*XC+col per M-subtile
    #pragma unroll
    for (int mt = 0; mt < 4; ++mt) {
        int px = w * 64 + mt * 16 + m;
        slot0[mt] = (px >> 5) * XC + (px & 31);
    }
    const int swz0 = ((g    ) ^ (m & 7)) << 4;    // bv byte slot, ck=0
    const int swz1 = ((g + 4) ^ (m & 7)) << 4;    // bv byte slot, ck=1
    int wrow[4];                                  // bv row byte within tap
    #pragma unroll
    for (int nt = 0; nt < 4; ++nt)
        wrow[nt] = (nt * 16 + m) * 128;

    float bs[4];
    #pragma unroll
    for (int nt = 0; nt < 4; ++nt)
        bs[nt] = bias[half * 64 + nt * 16 + m];

    // ---- x staging: main 18r x 32c x 32p = 18432 u32 units (36/thread),
    //      edge cols 32,33: 1152 units (2.25/thread). T14 split: ISSUE fills
    //      f0/f1 regs (before epilogue), WRITE converts+stores to LDS (after).
    float f0[39], f1[39];

    #define STAGE_ISSUE(nn) do {                                               \
        const float* xn_ = x + (size_t)(nn) * (CIN * HIN * WIN);               \
        _Pragma("unroll")                                                      \
        for (int k = 0; k < 36; ++k) {                                         \
            int u = tid + k * 512;                                             \
            int r_ = u >> 10, v_ = u & 1023, c_ = v_ & 31, p_ = v_ >> 5;       \
            int gh = oh0 + r_; if (gh > HIN - 1) gh = HIN - 1;                 \
            const float* s_ = xn_ + (size_t)(p_ * 2) * (HIN * WIN)             \
                              + gh * WIN + (ow0 + c_);                         \
            f0[k] = s_[0]; f1[k] = s_[HIN * WIN];                              \
        }                                                                      \
        _Pragma("unroll")                                                      \
        for (int k = 0; k < 3; ++k) {                                          \
            int e = tid + k * 512;                                             \
            if (e < 1152) {                                                    \
                int r_ = e >> 6, rem = e & 63;                                 \
                int c_ = 32 + (rem >> 5), p_ = rem & 31;                       \
                int gh = oh0 + r_; if (gh > HIN - 1) gh = HIN - 1;             \
                int gw = ow0 + c_; if (gw > WIN - 1) gw = WIN - 1;             \
                const float* s_ = xn_ + (size_t)(p_ * 2) * (HIN * WIN)         \
                                  + gh * WIN + gw;                             \
                f0[36 + k] = s_[0]; f1[36 + k] = s_[HIN * WIN];                \
            }                                                                  \
        }                                                                      \
    } while (0)

    #define STAGE_WRITE() do {                                                 \
        _Pragma("unroll")                                                      \
        for (int k = 0; k < 36; ++k) {                                         \
            int u = tid + k * 512;                                             \
            int r_ = u >> 10, v_ = u & 1023, c_ = v_ & 31, p_ = v_ >> 5;       \
            unsigned pk = (unsigned)f2bf(f0[k])                                \
                        | ((unsigned)f2bf(f1[k]) << 16);                       \
            ((unsigned*)sx)[(r_ * XC + c_) * (CIP / 2) + p_] = pk;             \
        }                                                                      \
        _Pragma("unroll")                                                      \
        for (int k = 0; k < 3; ++k) {                                          \
            int e = tid + k * 512;                                             \
            if (e < 1152) {                                                    \
                int r_ = e >> 6, rem = e & 63;                                 \
                int c_ = 32 + (rem >> 5), p_ = rem & 31;                       \
                unsigned pk = (unsigned)f2bf(f0[36 + k])                       \
                            | ((unsigned)f2bf(f1[36 + k]) << 16);              \
                ((unsigned*)sx)[(r_ * XC + c_) * (CIP / 2) + p_] = pk;         \
            }                                                                  \
        }                                                                      \
    } while (0)

    STAGE_ISSUE(0);
    STAGE_WRITE();
    __syncthreads();                              // wl + sx(0) ready

    const char* sxb = (const char*)sx;
    const char* wlb = (const char*)wl;

    for (int t = 0; t < NBATCH; ++t) {
        // ---- compute: 9 taps x 2 ck, barrier-free stretch, acc init = bias
        f32x4 acc[4][4];
        #pragma unroll
        for (int a = 0; a < 4; ++a)
            #pragma unroll
            for (int q2 = 0; q2 < 4; ++q2)
                acc[a][q2] = (f32x4){bs[q2], bs[q2], bs[q2], bs[q2]};

        __builtin_amdgcn_s_setprio(1);
        #pragma unroll
        for (int tap = 0; tap < 9; ++tap) {
            const int kh = tap / 3, kw = tap - kh * 3;
            const int abase = ((kh * XC + kw) * CIP + g8) * 2;   // bytes
            const int wbase = tap * 8192;                        // bytes
            #pragma unroll
            for (int ck = 0; ck < 2; ++ck) {
                bf16x8 av[4], bv[4];
                #pragma unroll
                for (int mt = 0; mt < 4; ++mt)
                    av[mt] = *(const bf16x8*)(sxb + slot0[mt] * 144
                                              + abase + ck * 64);
                const int swz = ck ? swz1 : swz0;
                #pragma unroll
                for (int nt = 0; nt < 4; ++nt)
                    bv[nt] = *(const bf16x8*)(wlb + wbase + wrow[nt] + swz);
                #pragma unroll
                for (int mt = 0; mt < 4; ++mt)
                    #pragma unroll
                    for (int nt = 0; nt < 4; ++nt)
                        acc[mt][nt] = __builtin_amdgcn_mfma_f32_16x16x32_bf16(
                            av[mt], bv[nt], acc[mt][nt], 0, 0, 0);
            }
        }
        __builtin_amdgcn_s_setprio(0);

        if (t < NBATCH - 1) STAGE_ISSUE(t + 1);   // loads drain under epilogue

        // ---- epilogue: mish2 + store (bias already in acc), n = t
        #pragma unroll
        for (int nt = 0; nt < 4; ++nt) {
            const int co = half * 64 + nt * 16 + m;
            float* ob = out + (size_t)(t * COUT + co) * HOUT * WOUT;
            #pragma unroll
            for (int mt = 0; mt < 4; ++mt) {
                int pb = w * 64 + mt * 16 + g * 4;
                int oh = oh0 + (pb >> 5);
                int ow = ow0 + (pb & 31);
                if (oh >= HOUT) continue;
                float v0 = mish2(acc[mt][nt][0]);
                float v1 = mish2(acc[mt][nt][1]);
                float v2 = mish2(acc[mt][nt][2]);
                float v3 = mish2(acc[mt][nt][3]);
                float* dst = ob + oh * WOUT + ow;
                if (ow + 3 < WOUT) {
                    dst[0] = v0; dst[1] = v1; dst[2] = v2; dst[3] = v3;
                } else {
                    if (ow     < WOUT) dst[0] = v0;
                    if (ow + 1 < WOUT) dst[1] = v1;
                    if (ow + 2 < WOUT) dst[2] = v2;
                    if (ow + 3 < WOUT) dst[3] = v3;
                }
            }
        }

        if (t < NBATCH - 1) {
            __syncthreads();                      // all waves done reading sx(t)
            STAGE_WRITE();                        // sx(t+1)
            __syncthreads();
        }
    }
    #undef STAGE_ISSUE
    #undef STAGE_WRITE
}

// ---------------------------------------------------------------------------
// Fallback (no workspace): r7's per-tap LDS weight staging from fp32 wgt.
// Own geometry: 128px x 128co blocks, grid (8,64,8).
// ---------------------------------------------------------------------------
#define F_PROWS 4
#define F_XR    6
#define F_XC    34

__global__ __launch_bounds__(256) void conv_mfma_fb(
    const float* __restrict__ x,
    const float* __restrict__ wgt,                // [COUT][CIN][3][3]
    const float* __restrict__ bias,
    float* __restrict__ out)
{
    __shared__ unsigned short sx[F_XR * F_XC * CIP];
    __shared__ unsigned short sw[COUT * CIP];

    const int tid = threadIdx.x;
    const int wt  = blockIdx.x;
    const int ht  = blockIdx.y;
    const int n   = blockIdx.z;
    const int oh0 = ht * F_PROWS, ow0 = wt * PCOLS;

    const float* xn = x + (size_t)n * CIN * HIN * WIN;

    for (int j = tid; j < F_XR * F_XC * (CIN / 2); j += 256) {
        int c = j % F_XC;
        int t = j / F_XC;
        int r = t % F_XR;
        int p = t / F_XR;
        int gh = oh0 + r; if (gh > HIN - 1) gh = HIN - 1;
        int gw = ow0 + c; if (gw > WIN - 1) gw = WIN - 1;
        const float* src = xn + (size_t)(p * 2) * (HIN * WIN) + gh * WIN + gw;
        float fa = src[0];
        float fb = src[HIN * WIN];
        unsigned pk = (unsigned)f2bf(fa) | ((unsigned)f2bf(fb) << 16);
        ((unsigned*)sx)[(r * F_XC + c) * (CIP / 2) + p] = pk;
    }

    const int w    = tid >> 6;
    const int lane = tid & 63;
    const int m    = lane & 15;
    const int g    = lane >> 4;
    const int px0  = (w & 1) * 64;
    const int cb   = (w >> 1) * 64;

    float bs[4];
    #pragma unroll
    for (int nt = 0; nt < 4; ++nt)
        bs[nt] = bias[cb + nt * 16 + m];

    int slot0[4];
    #pragma unroll
    for (int mt = 0; mt < 4; ++mt) {
        int px = px0 + mt * 16 + m;
        slot0[mt] = (px >> 5) * F_XC + (px & 31);
    }
    int bbase[4];
    #pragma unroll
    for (int nt = 0; nt < 4; ++nt)
        bbase[nt] = (cb + nt * 16 + m) * CIP + g * 8;

    f32x4 acc[4][4];
    #pragma unroll
    for (int a = 0; a < 4; ++a)
        #pragma unroll
        for (int q2 = 0; q2 < 4; ++q2)
            acc[a][q2] = (f32x4){bs[q2], bs[q2], bs[q2], bs[q2]};

    for (int tap = 0; tap < 9; ++tap) {
        int kh = tap / 3, kw = tap - kh * 3;
        __syncthreads();
        for (int i = tid; i < COUT * CIN; i += 256) {
            int co = i >> 6, ci = i & 63;
            sw[co * CIP + ci] = f2bf(wgt[(co * CIN + ci) * 9 + tap]);
        }
        __syncthreads();

        const int aoff = (kh * F_XC + kw) * CIP + g * 8;
        #pragma unroll
        for (int ck = 0; ck < 2; ++ck) {
            bf16x8 av[4], bv[4];
            #pragma unroll
            for (int mt = 0; mt < 4; ++mt)
                av[mt] = *(const bf16x8*)&sx[slot0[mt] * CIP + aoff + ck * 32];
            #pragma unroll
            for (int nt = 0; nt < 4; ++nt)
                bv[nt] = *(const bf16x8*)&sw[bbase[nt] + ck * 32];
            #pragma unroll
            for (int mt = 0; mt < 4; ++mt)
                #pragma unroll
                for (int nt = 0; nt < 4; ++nt)
                    acc[mt][nt] = __builtin_amdgcn_mfma_f32_16x16x32_bf16(
                        av[mt], bv[nt], acc[mt][nt], 0, 0, 0);
        }
    }

    #pragma unroll
    for (int nt = 0; nt < 4; ++nt) {
        int co = cb + nt * 16 + m;
        float* ob = out + (size_t)(n * COUT + co) * HOUT * WOUT;
        #pragma unroll
        for (int mt = 0; mt < 4; ++mt) {
            int pb = px0 + mt * 16 + g * 4;
            int oh = oh0 + (pb >> 5);
            int ow = ow0 + (pb & 31);
            if (oh >= HOUT) continue;
            float v0 = mish2(acc[mt][nt][0]);
            float v1 = mish2(acc[mt][nt][1]);
            float v2 = mish2(acc[mt][nt][2]);
            float v3 = mish2(acc[mt][nt][3]);
            float* dst = ob + oh * WOUT + ow;
            if (ow + 3 < WOUT) {
                dst[0] = v0; dst[1] = v1; dst[2] = v2; dst[3] = v3;
            } else {
                if (ow     < WOUT) dst[0] = v0;
                if (ow + 1 < WOUT) dst[1] = v1;
                if (ow + 2 < WOUT) dst[2] = v2;
                if (ow + 3 < WOUT) dst[3] = v3;
            }
        }
    }
}

extern "C" void kernel_launch(void* const* d_in, const int* in_sizes, int n_in,
                              void* d_out, int out_size, void* d_ws, size_t ws_size,
                              hipStream_t stream) {
    const float* x    = (const float*)d_in[0];
    const float* wgt  = (const float*)d_in[1];
    const float* bias = (const float*)d_in[2];
    float* out        = (float*)d_out;

    const size_t need = (size_t)2 * 9 * 64 * 64 * sizeof(unsigned short); // 147456
    int use_ws = (ws_size >= need) ? 1 : 0;
    unsigned short* wT = (unsigned short*)d_ws;

    if (use_ws) {
        wtrans_kernel<<<(2 * 9 * 64 * 64 + 255) / 256, 256, 0, stream>>>(wgt, wT);
        conv_persist<<<256, 512, 0, stream>>>(x, bias, wT, out);
    } else {
        dim3 grid((WOUT + PCOLS - 1) / PCOLS,      // 8
                  (HOUT + F_PROWS - 1) / F_PROWS,  // 64
                  NBATCH);                         // 8
        conv_mfma_fb<<<grid, 256, 0, stream>>>(x, wgt, bias, out);
    }
}

// Round 10
// 513.943 us; speedup vs baseline: 1.0218x; 1.0218x over previous
//
#include <hip/hip_runtime.h>

// Problem constants
#define NBATCH 8
#define CIN    64
#define HIN    256
#define WIN    256
#define COUT   128
#define HOUT   254
#define WOUT   254

// Tiling: block computes 128 pixels (4 rows x 32 cols) x 128 couts.
// 512 threads = 8 waves, each 64 px x 32 co (acc 4x2 f32x4 = 32 AGPR)
// -> ~<=120 unified regs/wave -> 4 waves/SIMD (16/CU) at 3 blocks/CU.
// K-loop: 9 taps x 2 chunks of 32 ci, 16x16x32 bf16 MFMA.
#define PROWS  4
#define PCOLS  32
#define XR     (PROWS + 2)   // 6 input rows
#define XC     (PCOLS + 2)   // 34 input cols
#define CIP    72            // padded ci stride in bf16 units (144B rows)

typedef __attribute__((ext_vector_type(8))) short bf16x8;  // MFMA A/B frag
typedef __attribute__((ext_vector_type(4))) float f32x4;   // MFMA C/D frag

__device__ __forceinline__ unsigned short f2bf(float f) {
    union { float f; unsigned u; } v; v.f = f;
    unsigned r = v.u + 0x7FFF + ((v.u >> 16) & 1);   // round-to-nearest-even
    return (unsigned short)(r >> 16);
}

// mish(v) = v*(1 - 2/((t+1)^2+1)), t=e^min(v,44). 8 insts, select-free.
__device__ __forceinline__ float mish1(float v) {
    float t = __expf(fminf(v, 44.0f));
    float s = t + 1.0f;
    float d = __builtin_fmaf(s, s, 1.0f);
    float r = __builtin_amdgcn_rcpf(d);
    return v * __builtin_fmaf(-2.0f, r, 1.0f);
}
__device__ __forceinline__ float mish2(float v) { return mish1(mish1(v)); }

// Pre-transpose weights: wgt[co][ci][kh][kw] fp32 -> wT[tap][co][ci] bf16.
__global__ __launch_bounds__(256) void wtrans_kernel(
    const float* __restrict__ wgt, unsigned short* __restrict__ wT)
{
    int i = blockIdx.x * 256 + threadIdx.x;       // over 9*128*64 = 73728
    if (i >= 9 * COUT * CIN) return;
    int ci  = i & (CIN - 1);
    int co  = (i >> 6) & (COUT - 1);
    int tap = i >> 13;
    wT[i] = f2bf(wgt[(co * CIN + ci) * 9 + tap]);
}

// ---------------------------------------------------------------------------
// r7 skeleton (best measured 227us: LDS-staged weights + async wT prefetch +
// lgkmcnt-only barrier + bias-in-acc + cheap mish), occupancy-raised:
// 512 threads / 8 half-size waves -> 16 waves/CU instead of 12.
// (Resubmit of r9 — infra failed twice; kernel audited, unchanged.)
// ---------------------------------------------------------------------------
__global__ __launch_bounds__(512, 4) void conv_mfma_ws(
    const float* __restrict__ x,                  // [NB][CIN][HIN][WIN]
    const float* __restrict__ bias,               // [COUT]
    const unsigned short* __restrict__ wT,        // [9][COUT][CIN] bf16
    float* __restrict__ out)                      // [NB][COUT][HOUT][WOUT]
{
    __shared__ unsigned short sx[XR * XC * CIP];  // 29376 B
    __shared__ unsigned short sw[COUT * CIP];     // 18432 B

    const int tid = threadIdx.x;
    const int wt  = blockIdx.x;                   // 0..7  (w tile)
    const int ht  = blockIdx.y;                   // 0..63 (h tile)
    const int n   = blockIdx.z;                   // 0..7
    const int oh0 = ht * PROWS, ow0 = wt * PCOLS;

    const float* xn = x + (size_t)n * CIN * HIN * WIN;

    // wave/lane decomposition: 8 waves, each computes 64 px x 32 co
    const int w    = tid >> 6;
    const int lane = tid & 63;
    const int m    = lane & 15;                   // A: pixel row / B: cout col
    const int g    = lane >> 4;                   // k-group (8 ci each)
    const int px0  = (w & 1) * 64;
    const int cb   = (w >> 1) * 32;               // co quarter

    // ---- prologue: issue tap-0 weight loads first (deepest latency hiding)
    bf16x8 wr0 = *(const bf16x8*)(wT + (tid      ) * 8);
    bf16x8 wr1 = *(const bf16x8*)(wT + (tid + 512) * 8);

    // bias per N-subtile
    float bs[2];
    #pragma unroll
    for (int nt = 0; nt < 2; ++nt)
        bs[nt] = bias[cb + nt * 16 + m];

    // ---- stage x tile: [r][c][ci] bf16, ci contiguous (padded to CIP).
    // Main part (c<32): 6144 u32 units, 512 threads -> 12 passes.
    #pragma unroll 4
    for (int k = 0; k < 12; ++k) {
        int u = tid + k * 512;                    // 0..6143
        int r = u >> 10;                          // 0..5
        int v = u & 1023;
        int c = v & 31;                           // 0..31
        int p = v >> 5;                           // ci pair 0..31
        int gh = oh0 + r; if (gh > HIN - 1) gh = HIN - 1;
        int gw = ow0 + c;                         // <= 224+31 = 255, in bounds
        const float* src = xn + (size_t)(p * 2) * (HIN * WIN) + gh * WIN + gw;
        float f0 = src[0];
        float f1 = src[HIN * WIN];
        unsigned pk = (unsigned)f2bf(f0) | ((unsigned)f2bf(f1) << 16);
        ((unsigned*)sx)[(r * XC + c) * (CIP / 2) + p] = pk;
    }
    // Edge cols c=32,33: 384 units < 512 threads -> single pass.
    if (tid < 384) {
        int r = tid >> 6;                         // 0..5
        int rem = tid & 63;
        int c = 32 + (rem >> 5);                  // 32..33
        int p = rem & 31;
        int gh = oh0 + r; if (gh > HIN - 1) gh = HIN - 1;
        int gw = ow0 + c; if (gw > WIN - 1) gw = WIN - 1;
        const float* src = xn + (size_t)(p * 2) * (HIN * WIN) + gh * WIN + gw;
        float f0 = src[0];
        float f1 = src[HIN * WIN];
        unsigned pk = (unsigned)f2bf(f0) | ((unsigned)f2bf(f1) << 16);
        ((unsigned*)sx)[(r * XC + c) * (CIP / 2) + p] = pk;
    }

    int slot0[4];                                 // (r*XC + c) per M-subtile
    #pragma unroll
    for (int mt = 0; mt < 4; ++mt) {
        int px = px0 + mt * 16 + m;
        slot0[mt] = (px >> 5) * XC + (px & 31);
    }
    int bbase[2];
    #pragma unroll
    for (int nt = 0; nt < 2; ++nt)
        bbase[nt] = (cb + nt * 16 + m) * CIP + g * 8;

    // acc init = bias (no per-output add in the epilogue)
    f32x4 acc[4][2];
    #pragma unroll
    for (int a = 0; a < 4; ++a)
        #pragma unroll
        for (int b = 0; b < 2; ++b)
            acc[a][b] = (f32x4){bs[b], bs[b], bs[b], bs[b]};

    // sw write slots (static per thread; 1024 16B-chunks over 512 threads)
    const int sw0 = ((tid      ) >> 3) * CIP + ((tid      ) & 7) * 8;
    const int sw1 = ((tid + 512) >> 3) * CIP + ((tid + 512) & 7) * 8;

    #pragma unroll 1
    for (int tap = 0; tap < 9; ++tap) {
        // (a) full barrier: all waves done reading sw[tap-1]; 1st iter also
        // covers the sx stage. In-flight wT loads were issued a whole tap
        // ago -> the vmcnt(0) drain here is nearly free.
        __syncthreads();

        *(bf16x8*)&sw[sw0] = wr0;
        *(bf16x8*)&sw[sw1] = wr1;

        if (tap < 8) {                            // issue NEXT tap's loads now
            const unsigned short* wp = wT + (tap + 1) * (COUT * CIN);
            wr0 = *(const bf16x8*)(wp + (tid      ) * 8);
            wr1 = *(const bf16x8*)(wp + (tid + 512) * 8);
        }

        // (b) raw barrier: wait ONLY the ds_writes (lgkmcnt), leave the
        // just-issued global loads (vmcnt) in flight across the MFMA phase.
        asm volatile("s_waitcnt lgkmcnt(0)\n\ts_barrier" ::: "memory");

        const int kh = tap / 3, kw = tap - kh * 3;
        const int aoff = (kh * XC + kw) * CIP + g * 8;

        __builtin_amdgcn_s_setprio(1);
        #pragma unroll
        for (int ck = 0; ck < 2; ++ck) {
            bf16x8 av[4], bv[2];
            #pragma unroll
            for (int mt = 0; mt < 4; ++mt)
                av[mt] = *(const bf16x8*)&sx[slot0[mt] * CIP + aoff + ck * 32];
            #pragma unroll
            for (int nt = 0; nt < 2; ++nt)
                bv[nt] = *(const bf16x8*)&sw[bbase[nt] + ck * 32];
            #pragma unroll
            for (int mt = 0; mt < 4; ++mt)
                #pragma unroll
                for (int nt = 0; nt < 2; ++nt)
                    acc[mt][nt] = __builtin_amdgcn_mfma_f32_16x16x32_bf16(
                        av[mt], bv[nt], acc[mt][nt], 0, 0, 0);
        }
        __builtin_amdgcn_s_setprio(0);
    }

    // ---- epilogue: mish2 + store (bias already in acc).
    // C/D layout (m89-verified): col(n-dim)=lane&15, row(m-dim)=(lane>>4)*4+reg.
    #pragma unroll
    for (int nt = 0; nt < 2; ++nt) {
        int co = cb + nt * 16 + m;
        float* ob = out + (size_t)(n * COUT + co) * HOUT * WOUT;
        #pragma unroll
        for (int mt = 0; mt < 4; ++mt) {
            int pb = px0 + mt * 16 + g * 4;
            int oh = oh0 + (pb >> 5);
            int ow = ow0 + (pb & 31);
            if (oh >= HOUT) continue;
            float v0 = mish2(acc[mt][nt][0]);
            float v1 = mish2(acc[mt][nt][1]);
            float v2 = mish2(acc[mt][nt][2]);
            float v3 = mish2(acc[mt][nt][3]);
            float* dst = ob + oh * WOUT + ow;
            if (ow + 3 < WOUT) {
                dst[0] = v0; dst[1] = v1; dst[2] = v2; dst[3] = v3;
            } else {
                if (ow     < WOUT) dst[0] = v0;
                if (ow + 1 < WOUT) dst[1] = v1;
                if (ow + 2 < WOUT) dst[2] = v2;
                if (ow + 3 < WOUT) dst[3] = v3;
            }
        }
    }
}

// ---------------------------------------------------------------------------
// Fallback (no workspace): per-tap LDS weight staging from fp32 wgt.
// ---------------------------------------------------------------------------
__global__ __launch_bounds__(256) void conv_mfma_fb(
    const float* __restrict__ x,
    const float* __restrict__ wgt,                // [COUT][CIN][3][3]
    const float* __restrict__ bias,
    float* __restrict__ out)
{
    __shared__ unsigned short sx[XR * XC * CIP];
    __shared__ unsigned short sw[COUT * CIP];

    const int tid = threadIdx.x;
    const int wt  = blockIdx.x;
    const int ht  = blockIdx.y;
    const int n   = blockIdx.z;
    const int oh0 = ht * PROWS, ow0 = wt * PCOLS;

    const float* xn = x + (size_t)n * CIN * HIN * WIN;

    for (int j = tid; j < XR * XC * (CIN / 2); j += 256) {
        int c = j % XC;
        int t = j / XC;
        int r = t % XR;
        int p = t / XR;
        int gh = oh0 + r; if (gh > HIN - 1) gh = HIN - 1;
        int gw = ow0 + c; if (gw > WIN - 1) gw = WIN - 1;
        const float* src = xn + (size_t)(p * 2) * (HIN * WIN) + gh * WIN + gw;
        float f0 = src[0];
        float f1 = src[HIN * WIN];
        unsigned pk = (unsigned)f2bf(f0) | ((unsigned)f2bf(f1) << 16);
        ((unsigned*)sx)[(r * XC + c) * (CIP / 2) + p] = pk;
    }

    const int w    = tid >> 6;
    const int lane = tid & 63;
    const int m    = lane & 15;
    const int g    = lane >> 4;
    const int px0  = (w & 1) * 64;
    const int cb   = (w >> 1) * 64;

    float bs[4];
    #pragma unroll
    for (int nt = 0; nt < 4; ++nt)
        bs[nt] = bias[cb + nt * 16 + m];

    int slot0[4];
    #pragma unroll
    for (int mt = 0; mt < 4; ++mt) {
        int px = px0 + mt * 16 + m;
        slot0[mt] = (px >> 5) * XC + (px & 31);
    }
    int bbase[4];
    #pragma unroll
    for (int nt = 0; nt < 4; ++nt)
        bbase[nt] = (cb + nt * 16 + m) * CIP + g * 8;

    f32x4 acc[4][4];
    #pragma unroll
    for (int a = 0; a < 4; ++a)
        #pragma unroll
        for (int b = 0; b < 4; ++b)
            acc[a][b] = (f32x4){bs[b], bs[b], bs[b], bs[b]};

    for (int tap = 0; tap < 9; ++tap) {
        int kh = tap / 3, kw = tap - kh * 3;
        __syncthreads();
        for (int i = tid; i < COUT * CIN; i += 256) {
            int co = i >> 6, ci = i & 63;
            sw[co * CIP + ci] = f2bf(wgt[(co * CIN + ci) * 9 + tap]);
        }
        __syncthreads();

        const int aoff = (kh * XC + kw) * CIP + g * 8;
        #pragma unroll
        for (int ck = 0; ck < 2; ++ck) {
            bf16x8 av[4], bv[4];
            #pragma unroll
            for (int mt = 0; mt < 4; ++mt)
                av[mt] = *(const bf16x8*)&sx[slot0[mt] * CIP + aoff + ck * 32];
            #pragma unroll
            for (int nt = 0; nt < 4; ++nt)
                bv[nt] = *(const bf16x8*)&sw[bbase[nt] + ck * 32];
            #pragma unroll
            for (int mt = 0; mt < 4; ++mt)
                #pragma unroll
                for (int nt = 0; nt < 4; ++nt)
                    acc[mt][nt] = __builtin_amdgcn_mfma_f32_16x16x32_bf16(
                        av[mt], bv[nt], acc[mt][nt], 0, 0, 0);
        }
    }

    #pragma unroll
    for (int nt = 0; nt < 4; ++nt) {
        int co = cb + nt * 16 + m;
        float* ob = out + (size_t)(n * COUT + co) * HOUT * WOUT;
        #pragma unroll
        for (int mt = 0; mt < 4; ++mt) {
            int pb = px0 + mt * 16 + g * 4;
            int oh = oh0 + (pb >> 5);
            int ow = ow0 + (pb & 31);
            if (oh >= HOUT) continue;
            float v0 = mish2(acc[mt][nt][0]);
            float v1 = mish2(acc[mt][nt][1]);
            float v2 = mish2(acc[mt][nt][2]);
            float v3 = mish2(acc[mt][nt][3]);
            float* dst = ob + oh * WOUT + ow;
            if (ow + 3 < WOUT) {
                dst[0] = v0; dst[1] = v1; dst[2] = v2; dst[3] = v3;
            } else {
                if (ow     < WOUT) dst[0] = v0;
                if (ow + 1 < WOUT) dst[1] = v1;
                if (ow + 2 < WOUT) dst[2] = v2;
                if (ow + 3 < WOUT) dst[3] = v3;
            }
        }
    }
}

extern "C" void kernel_launch(void* const* d_in, const int* in_sizes, int n_in,
                              void* d_out, int out_size, void* d_ws, size_t ws_size,
                              hipStream_t stream) {
    const float* x    = (const float*)d_in[0];
    const float* wgt  = (const float*)d_in[1];
    const float* bias = (const float*)d_in[2];
    float* out        = (float*)d_out;

    const size_t need = (size_t)9 * COUT * CIN * sizeof(unsigned short);  // 147456 B
    int use_ws = (ws_size >= need) ? 1 : 0;
    unsigned short* wT = (unsigned short*)d_ws;

    dim3 grid((WOUT + PCOLS - 1) / PCOLS,   // 8
              (HOUT + PROWS - 1) / PROWS,   // 64
              NBATCH);                      // 8

    if (use_ws) {
        wtrans_kernel<<<(9 * COUT * CIN + 255) / 256, 256, 0, stream>>>(wgt, wT);
        conv_mfma_ws<<<grid, 512, 0, stream>>>(x, bias, wT, out);
    } else {
        conv_mfma_fb<<<grid, 256, 0, stream>>>(x, wgt, bias, out);
    }
}